// Round 1
// baseline (721.818 us; speedup 1.0000x reference)
//
#include <hip/hip_runtime.h>
#include <math.h>

// Problem constants (match reference file)
#define N_NODES 100000
#define N_EDGES 1600000
#define TOT_EDGES (N_EDGES + N_NODES)   // with self-loops
#define HID 64

// ---------------------------------------------------------------------------
// CSR build: count -> exclusive scan -> scatter (sorted by dst)
// ---------------------------------------------------------------------------

__global__ void k_init_cnt(int* cnt) {
    int i = blockIdx.x * blockDim.x + threadIdx.x;
    if (i < N_NODES) cnt[i] = 1;  // self-loop
}

__global__ void k_count(const int* __restrict__ dst, int* __restrict__ cnt) {
    int e = blockIdx.x * blockDim.x + threadIdx.x;
    if (e < N_EDGES) atomicAdd(&cnt[dst[e]], 1);
}

// block-wise partial sums (256 elems per block)
__global__ void k_scan1(const int* __restrict__ cnt, int* __restrict__ partial) {
    __shared__ int lds[256];
    int i = blockIdx.x * 256 + threadIdx.x;
    int v = (i < N_NODES) ? cnt[i] : 0;
    lds[threadIdx.x] = v;
    __syncthreads();
    for (int s = 128; s > 0; s >>= 1) {
        if (threadIdx.x < s) lds[threadIdx.x] += lds[threadIdx.x + s];
        __syncthreads();
    }
    if (threadIdx.x == 0) partial[blockIdx.x] = lds[0];
}

// single-block exclusive scan of the partials (nb <= 512)
__global__ void k_scan2(int* __restrict__ partial, int nb) {
    __shared__ int lds[512];
    int t = threadIdx.x;
    int v = (t < nb) ? partial[t] : 0;
    lds[t] = v;
    __syncthreads();
    for (int off = 1; off < 512; off <<= 1) {
        int add = (t >= off) ? lds[t - off] : 0;
        __syncthreads();
        lds[t] += add;
        __syncthreads();
    }
    if (t < nb) partial[t] = lds[t] - v;  // exclusive
}

// apply: rowoff, write-cursors, dinv = rsqrt(deg), xs = x * dinv  (fused)
__global__ void k_scan3(const int* __restrict__ cnt, const int* __restrict__ partial,
                        int* __restrict__ rowoff, int* __restrict__ wcur,
                        float* __restrict__ dinv, const float* __restrict__ x,
                        float* __restrict__ xs) {
    __shared__ int lds[256];
    int i = blockIdx.x * 256 + threadIdx.x;
    int v = (i < N_NODES) ? cnt[i] : 0;
    lds[threadIdx.x] = v;
    __syncthreads();
    for (int off = 1; off < 256; off <<= 1) {
        int add = (threadIdx.x >= off) ? lds[threadIdx.x - off] : 0;
        __syncthreads();
        lds[threadIdx.x] += add;
        __syncthreads();
    }
    if (i < N_NODES) {
        int excl = partial[blockIdx.x] + lds[threadIdx.x] - v;
        rowoff[i] = excl;
        wcur[i]   = excl;
        float di = rsqrtf((float)v);  // deg >= 1 always (self-loop)
        dinv[i] = di;
        float4 xv = ((const float4*)x)[i];
        xv.x *= di; xv.y *= di; xv.z *= di; xv.w *= di;
        ((float4*)xs)[i] = xv;
        if (i == N_NODES - 1) rowoff[N_NODES] = excl + v;
    }
}

__global__ void k_scatter(const int* __restrict__ src, const int* __restrict__ dst,
                          int* __restrict__ wcur, int* __restrict__ srcs) {
    int e = blockIdx.x * blockDim.x + threadIdx.x;
    if (e >= TOT_EDGES) return;
    int s_, d_;
    if (e < N_EDGES) { s_ = src[e]; d_ = dst[e]; }
    else             { s_ = e - N_EDGES; d_ = s_; }
    int pos = atomicAdd(&wcur[d_], 1);
    srcs[pos] = s_;
}

// ---------------------------------------------------------------------------
// GCN1 aggregation in 4-channel input space (thread per node, float4 gathers)
// aggx[i] = dinv[i] * sum_j (x[j] * dinv[j])
// ---------------------------------------------------------------------------
__global__ void k_agg_x(const int* __restrict__ rowoff, const int* __restrict__ srcs,
                        const float* __restrict__ xs, const float* __restrict__ dinv,
                        float* __restrict__ aggx) {
    int i = blockIdx.x * blockDim.x + threadIdx.x;
    if (i >= N_NODES) return;
    int b = rowoff[i], en = rowoff[i + 1];
    float4 acc = {0.f, 0.f, 0.f, 0.f};
    for (int p = b; p < en; ++p) {
        int s = srcs[p];
        float4 v = ((const float4*)xs)[s];
        acc.x += v.x; acc.y += v.y; acc.z += v.z; acc.w += v.w;
    }
    float di = dinv[i];
    acc.x *= di; acc.y *= di; acc.z *= di; acc.w *= di;
    ((float4*)aggx)[i] = acc;
}

// ---------------------------------------------------------------------------
// h1 = relu(aggx @ W1 + b1); hl = h1 @ Wl; hr = h1 @ Wr   (wave per node)
// grid: 25000 blocks x 256 (4 nodes/block), N divisible by 4 -> no tail
// ---------------------------------------------------------------------------
__global__ void k_hlhr(const float* __restrict__ aggx, const float* __restrict__ W1,
                       const float* __restrict__ b1, const float* __restrict__ Wl,
                       const float* __restrict__ Wr, float* __restrict__ hl,
                       float* __restrict__ hr) {
    __shared__ float lds[4][HID];
    int lane = threadIdx.x & 63;
    int w    = threadIdx.x >> 6;
    int i    = blockIdx.x * 4 + w;
    float4 a = ((const float4*)aggx)[i];
    float h = a.x * W1[0 * HID + lane] + a.y * W1[1 * HID + lane] +
              a.z * W1[2 * HID + lane] + a.w * W1[3 * HID + lane] + b1[lane];
    h = fmaxf(h, 0.f);
    lds[w][lane] = h;
    __syncthreads();
    float al = 0.f, ar = 0.f;
#pragma unroll 8
    for (int k = 0; k < HID; ++k) {
        float t = lds[w][k];
        al += t * Wl[k * HID + lane];
        ar += t * Wr[k * HID + lane];
    }
    hl[i * HID + lane] = al;
    hr[i * HID + lane] = ar;
}

// ---------------------------------------------------------------------------
// GATv2 with online softmax, single pass over in-edges (wave per node).
// Epilogue fuses: + gat_b, relu, * dinv  ->  s2 (input to GCN2 aggregation)
// ---------------------------------------------------------------------------
__global__ void k_gat(const int* __restrict__ rowoff, const int* __restrict__ srcs,
                      const float* __restrict__ hl, const float* __restrict__ hr,
                      const float* __restrict__ att, const float* __restrict__ gat_b,
                      const float* __restrict__ dinv, float* __restrict__ s2) {
    int lane = threadIdx.x & 63;
    int w    = threadIdx.x >> 6;
    int i    = blockIdx.x * 4 + w;
    float hri  = hr[i * HID + lane];
    float attc = att[lane];  // (2,32) flat == lane
    float m = -INFINITY, denom = 0.f, acc = 0.f;
    int b = rowoff[i], en = rowoff[i + 1];
    for (int p = b; p < en; ++p) {
        int s = srcs[p];
        float v = hl[s * HID + lane];
        float e = v + hri;
        e = (e > 0.f) ? e : 0.2f * e;  // leaky_relu 0.2
        float t = e * attc;
        // reduce within each 32-lane half (per-head logit); masks<32 stay in half
        t += __shfl_xor(t, 1);
        t += __shfl_xor(t, 2);
        t += __shfl_xor(t, 4);
        t += __shfl_xor(t, 8);
        t += __shfl_xor(t, 16);
        float logit = t;
        float nm = fmaxf(m, logit);
        float sc = __expf(m - nm);      // first iter: exp(-inf)=0
        float ex = __expf(logit - nm);
        denom = denom * sc + ex;
        acc   = acc * sc + ex * v;
        m = nm;
    }
    float o = acc / (denom + 1e-16f);
    o = fmaxf(o + gat_b[lane], 0.f);
    s2[i * HID + lane] = o * dinv[i];
}

// ---------------------------------------------------------------------------
// GCN2 aggregation + transform + bias + relu + final linear, all fused.
// out[i] = relu( (dinv[i]*sum_j s2[j]) @ W2 + b2 ) @ out_w + out_b
// ---------------------------------------------------------------------------
__global__ void k_agg2_out(const int* __restrict__ rowoff, const int* __restrict__ srcs,
                           const float* __restrict__ s2, const float* __restrict__ dinv,
                           const float* __restrict__ W2, const float* __restrict__ b2,
                           const float* __restrict__ out_w, const float* __restrict__ out_b,
                           float* __restrict__ out) {
    __shared__ float lds[4][HID];
    int lane = threadIdx.x & 63;
    int w    = threadIdx.x >> 6;
    int i    = blockIdx.x * 4 + w;
    float acc = 0.f;
    int b = rowoff[i], en = rowoff[i + 1];
    for (int p = b; p < en; ++p) {
        int s = srcs[p];
        acc += s2[s * HID + lane];
    }
    lds[w][lane] = acc * dinv[i];
    __syncthreads();
    float z = 0.f;
#pragma unroll 8
    for (int k = 0; k < HID; ++k) z += lds[w][k] * W2[k * HID + lane];
    z = fmaxf(z + b2[lane], 0.f);
    float y = z * out_w[lane];  // out_w is (64,1) flat
    y += __shfl_xor(y, 32);
    y += __shfl_xor(y, 16);
    y += __shfl_xor(y, 8);
    y += __shfl_xor(y, 4);
    y += __shfl_xor(y, 2);
    y += __shfl_xor(y, 1);
    if (lane == 0) out[i] = y + out_b[0];
}

// ---------------------------------------------------------------------------

extern "C" void kernel_launch(void* const* d_in, const int* in_sizes, int n_in,
                              void* d_out, int out_size, void* d_ws, size_t ws_size,
                              hipStream_t stream) {
    const float* x   = (const float*)d_in[0];
    const int*   ei  = (const int*)d_in[1];
    const int*   src = ei;
    const int*   dst = ei + N_EDGES;
    const float* W1  = (const float*)d_in[2];
    const float* b1  = (const float*)d_in[3];
    const float* Wl  = (const float*)d_in[4];
    const float* Wr  = (const float*)d_in[5];
    const float* att = (const float*)d_in[6];
    const float* gb  = (const float*)d_in[7];
    const float* W2  = (const float*)d_in[8];
    const float* b2  = (const float*)d_in[9];
    const float* ow  = (const float*)d_in[10];
    const float* ob  = (const float*)d_in[11];
    float* out = (float*)d_out;

    // workspace layout (256B-aligned regions)
    char* ws = (char*)d_ws;
    size_t o = 0;
    auto alloc = [&](size_t bytes) { size_t r = o; o = (o + bytes + 255) & ~(size_t)255; return r; };
    int*   cnt     = (int*)  (ws + alloc((size_t)N_NODES * 4));
    int*   rowoff  = (int*)  (ws + alloc((size_t)(N_NODES + 1) * 4));
    int*   wcur    = (int*)  (ws + alloc((size_t)N_NODES * 4));
    int*   partial = (int*)  (ws + alloc(512 * 4));
    float* dinv    = (float*)(ws + alloc((size_t)N_NODES * 4));
    float* xs      = (float*)(ws + alloc((size_t)N_NODES * 4 * 4));
    float* aggx    = (float*)(ws + alloc((size_t)N_NODES * 4 * 4));
    int*   srcs    = (int*)  (ws + alloc((size_t)TOT_EDGES * 4));
    float* hl      = (float*)(ws + alloc((size_t)N_NODES * HID * 4));
    float* hr      = (float*)(ws + alloc((size_t)N_NODES * HID * 4));
    float* s2      = (float*)(ws + alloc((size_t)N_NODES * HID * 4));
    (void)ws_size; (void)n_in; (void)in_sizes; (void)out_size;

    const int nbN   = (N_NODES + 255) / 256;      // 391
    const int nbE   = (N_EDGES + 255) / 256;      // 6250
    const int nbTE  = (TOT_EDGES + 255) / 256;    // 6641
    const int nbW   = N_NODES / 4;                // 25000 (wave-per-node kernels, exact)

    k_init_cnt<<<nbN, 256, 0, stream>>>(cnt);
    k_count<<<nbE, 256, 0, stream>>>(dst, cnt);
    k_scan1<<<nbN, 256, 0, stream>>>(cnt, partial);
    k_scan2<<<1, 512, 0, stream>>>(partial, nbN);
    k_scan3<<<nbN, 256, 0, stream>>>(cnt, partial, rowoff, wcur, dinv, x, xs);
    k_scatter<<<nbTE, 256, 0, stream>>>(src, dst, wcur, srcs);
    k_agg_x<<<nbN, 256, 0, stream>>>(rowoff, srcs, xs, dinv, aggx);
    k_hlhr<<<nbW, 256, 0, stream>>>(aggx, W1, b1, Wl, Wr, hl, hr);
    k_gat<<<nbW, 256, 0, stream>>>(rowoff, srcs, hl, hr, att, gb, dinv, s2);
    k_agg2_out<<<nbW, 256, 0, stream>>>(rowoff, srcs, s2, dinv, W2, b2, ow, ob, out);
}

// Round 2
// 497.704 us; speedup vs baseline: 1.4503x; 1.4503x over previous
//
#include <hip/hip_runtime.h>
#include <math.h>

// Problem constants (match reference file)
#define N_NODES 100000
#define N_EDGES 1600000
#define TOT_EDGES (N_EDGES + N_NODES)   // with self-loops
#define HID 64

// ---------------------------------------------------------------------------
// CSR build: count -> exclusive scan -> scatter (sorted by dst)
// ---------------------------------------------------------------------------

__global__ void k_init_cnt(int* cnt) {
    int i = blockIdx.x * blockDim.x + threadIdx.x;
    if (i < N_NODES) cnt[i] = 1;  // self-loop
}

__global__ void k_count(const int* __restrict__ dst, int* __restrict__ cnt) {
    int e = blockIdx.x * blockDim.x + threadIdx.x;
    if (e < N_EDGES) atomicAdd(&cnt[dst[e]], 1);
}

// block-wise partial sums (256 elems per block)
__global__ void k_scan1(const int* __restrict__ cnt, int* __restrict__ partial) {
    __shared__ int lds[256];
    int i = blockIdx.x * 256 + threadIdx.x;
    int v = (i < N_NODES) ? cnt[i] : 0;
    lds[threadIdx.x] = v;
    __syncthreads();
    for (int s = 128; s > 0; s >>= 1) {
        if (threadIdx.x < s) lds[threadIdx.x] += lds[threadIdx.x + s];
        __syncthreads();
    }
    if (threadIdx.x == 0) partial[blockIdx.x] = lds[0];
}

// single-block exclusive scan of the partials (nb <= 512)
__global__ void k_scan2(int* __restrict__ partial, int nb) {
    __shared__ int lds[512];
    int t = threadIdx.x;
    int v = (t < nb) ? partial[t] : 0;
    lds[t] = v;
    __syncthreads();
    for (int off = 1; off < 512; off <<= 1) {
        int add = (t >= off) ? lds[t - off] : 0;
        __syncthreads();
        lds[t] += add;
        __syncthreads();
    }
    if (t < nb) partial[t] = lds[t] - v;  // exclusive
}

// apply: rowoff, write-cursors, dinv = rsqrt(deg), xs = x * dinv  (fused)
__global__ void k_scan3(const int* __restrict__ cnt, const int* __restrict__ partial,
                        int* __restrict__ rowoff, int* __restrict__ wcur,
                        float* __restrict__ dinv, const float* __restrict__ x,
                        float* __restrict__ xs) {
    __shared__ int lds[256];
    int i = blockIdx.x * 256 + threadIdx.x;
    int v = (i < N_NODES) ? cnt[i] : 0;
    lds[threadIdx.x] = v;
    __syncthreads();
    for (int off = 1; off < 256; off <<= 1) {
        int add = (threadIdx.x >= off) ? lds[threadIdx.x - off] : 0;
        __syncthreads();
        lds[threadIdx.x] += add;
        __syncthreads();
    }
    if (i < N_NODES) {
        int excl = partial[blockIdx.x] + lds[threadIdx.x] - v;
        rowoff[i] = excl;
        wcur[i]   = excl;
        float di = rsqrtf((float)v);  // deg >= 1 always (self-loop)
        dinv[i] = di;
        float4 xv = ((const float4*)x)[i];
        xv.x *= di; xv.y *= di; xv.z *= di; xv.w *= di;
        ((float4*)xs)[i] = xv;
        if (i == N_NODES - 1) rowoff[N_NODES] = excl + v;
    }
}

__global__ void k_scatter(const int* __restrict__ src, const int* __restrict__ dst,
                          int* __restrict__ wcur, int* __restrict__ srcs) {
    int e = blockIdx.x * blockDim.x + threadIdx.x;
    if (e >= TOT_EDGES) return;
    int s_, d_;
    if (e < N_EDGES) { s_ = src[e]; d_ = dst[e]; }
    else             { s_ = e - N_EDGES; d_ = s_; }
    int pos = atomicAdd(&wcur[d_], 1);
    srcs[pos] = s_;
}

// ---------------------------------------------------------------------------
// GCN1 aggregation in 4-channel input space.
// Wave handles 4 nodes (16 lanes each, edge-per-lane float4 gathers).
// aggx[i] = dinv[i] * sum_j (x[j] * dinv[j])
// grid: N/16 = 6250 blocks x 256
// ---------------------------------------------------------------------------
__global__ void k_agg_x(const int* __restrict__ rowoff, const int* __restrict__ srcs,
                        const float* __restrict__ xs, const float* __restrict__ dinv,
                        float* __restrict__ aggx) {
    int lane = threadIdx.x & 63;
    int w    = threadIdx.x >> 6;
    int g    = lane >> 4;   // node within wave
    int q    = lane & 15;   // edge slot
    int i    = blockIdx.x * 16 + w * 4 + g;
    int b = rowoff[i], en = rowoff[i + 1];
    float4 acc = {0.f, 0.f, 0.f, 0.f};
    for (int p = b + q; p < en; p += 16) {
        int s = srcs[p];
        float4 v = ((const float4*)xs)[s];
        acc.x += v.x; acc.y += v.y; acc.z += v.z; acc.w += v.w;
    }
#pragma unroll
    for (int mask = 1; mask <= 8; mask <<= 1) {
        acc.x += __shfl_xor(acc.x, mask);
        acc.y += __shfl_xor(acc.y, mask);
        acc.z += __shfl_xor(acc.z, mask);
        acc.w += __shfl_xor(acc.w, mask);
    }
    if (q == 0) {
        float di = dinv[i];
        acc.x *= di; acc.y *= di; acc.z *= di; acc.w *= di;
        ((float4*)aggx)[i] = acc;
    }
}

// ---------------------------------------------------------------------------
// h1 = relu(aggx @ W1 + b1); hl = h1 @ Wl; hr = h1 @ Wr   (wave per node)
// ---------------------------------------------------------------------------
__global__ void k_hlhr(const float* __restrict__ aggx, const float* __restrict__ W1,
                       const float* __restrict__ b1, const float* __restrict__ Wl,
                       const float* __restrict__ Wr, float* __restrict__ hl,
                       float* __restrict__ hr) {
    __shared__ float lds[4][HID];
    int lane = threadIdx.x & 63;
    int w    = threadIdx.x >> 6;
    int i    = blockIdx.x * 4 + w;
    float4 a = ((const float4*)aggx)[i];
    float h = a.x * W1[0 * HID + lane] + a.y * W1[1 * HID + lane] +
              a.z * W1[2 * HID + lane] + a.w * W1[3 * HID + lane] + b1[lane];
    h = fmaxf(h, 0.f);
    lds[w][lane] = h;
    __syncthreads();
    float al = 0.f, ar = 0.f;
#pragma unroll 8
    for (int k = 0; k < HID; ++k) {
        float t = lds[w][k];
        al += t * Wl[k * HID + lane];
        ar += t * Wr[k * HID + lane];
    }
    hl[i * HID + lane] = al;
    hr[i * HID + lane] = ar;
}

// ---------------------------------------------------------------------------
// GATv2 online softmax, 4 edges in flight per wave-iteration.
// Lane l: edge group g=l>>4, channel quad q=l&15 (c0=4q, head=q>>3).
// Each 16-lane group runs an independent online softmax over edges b+g, b+g+4,...
// then groups merge via shfl_xor(16,32) online-softmax combine.
// Epilogue fuses: + gat_b, relu, * dinv  ->  s2 (input to GCN2 aggregation)
// ---------------------------------------------------------------------------
__global__ void k_gat(const int* __restrict__ rowoff, const int* __restrict__ srcs,
                      const float* __restrict__ hl, const float* __restrict__ hr,
                      const float* __restrict__ att, const float* __restrict__ gat_b,
                      const float* __restrict__ dinv, float* __restrict__ s2) {
    int lane = threadIdx.x & 63;
    int w    = threadIdx.x >> 6;
    int g    = lane >> 4;
    int q    = lane & 15;
    int c0   = q * 4;
    int i    = blockIdx.x * 4 + w;
    const float4 hri = *(const float4*)(hr + (size_t)i * HID + c0);
    const float4 a4  = *(const float4*)(att + c0);
    float  m = -1e30f, denom = 0.f;
    float4 acc = {0.f, 0.f, 0.f, 0.f};
    int b = rowoff[i], en = rowoff[i + 1];
    for (int p = b + g; p < en; p += 4) {
        int s = srcs[p];
        const float4 v = *(const float4*)(hl + (size_t)s * HID + c0);
        float4 e;
        e.x = v.x + hri.x; e.y = v.y + hri.y; e.z = v.z + hri.z; e.w = v.w + hri.w;
        e.x = (e.x > 0.f) ? e.x : 0.2f * e.x;
        e.y = (e.y > 0.f) ? e.y : 0.2f * e.y;
        e.z = (e.z > 0.f) ? e.z : 0.2f * e.z;
        e.w = (e.w > 0.f) ? e.w : 0.2f * e.w;
        float t = e.x * a4.x + e.y * a4.y + e.z * a4.z + e.w * a4.w;
        // per-head logit: reduce across the 8 lanes of this group-half
        t += __shfl_xor(t, 1);
        t += __shfl_xor(t, 2);
        t += __shfl_xor(t, 4);
        float logit = t;
        float nm = fmaxf(m, logit);
        float sc = __expf(m - nm);
        float ex = __expf(logit - nm);
        denom = denom * sc + ex;
        acc.x = acc.x * sc + ex * v.x;
        acc.y = acc.y * sc + ex * v.y;
        acc.z = acc.z * sc + ex * v.z;
        acc.w = acc.w * sc + ex * v.w;
        m = nm;
    }
    // merge the 4 groups' online states (same q -> same channels/head)
#pragma unroll
    for (int mask = 16; mask <= 32; mask <<= 1) {
        float m2 = __shfl_xor(m, mask);
        float d2 = __shfl_xor(denom, mask);
        float ax = __shfl_xor(acc.x, mask);
        float ay = __shfl_xor(acc.y, mask);
        float az = __shfl_xor(acc.z, mask);
        float aw = __shfl_xor(acc.w, mask);
        float nm = fmaxf(m, m2);
        float sa = __expf(m - nm);
        float sb = __expf(m2 - nm);
        denom = denom * sa + d2 * sb;
        acc.x = acc.x * sa + ax * sb;
        acc.y = acc.y * sa + ay * sb;
        acc.z = acc.z * sa + az * sb;
        acc.w = acc.w * sa + aw * sb;
        m = nm;
    }
    float inv = 1.f / (denom + 1e-16f);
    const float4 gb = *(const float4*)(gat_b + c0);
    float di = dinv[i];
    float4 o;
    o.x = fmaxf(acc.x * inv + gb.x, 0.f) * di;
    o.y = fmaxf(acc.y * inv + gb.y, 0.f) * di;
    o.z = fmaxf(acc.z * inv + gb.z, 0.f) * di;
    o.w = fmaxf(acc.w * inv + gb.w, 0.f) * di;
    if (g == 0) *(float4*)(s2 + (size_t)i * HID + c0) = o;
}

// ---------------------------------------------------------------------------
// GCN2 aggregation + transform + bias + relu + final linear, all fused.
// 4 edges per wave-iteration (lane: group g=l>>4, quad q=l&15).
// out[i] = relu( (dinv[i]*sum_j s2[j]) @ W2 + b2 ) @ out_w + out_b
// ---------------------------------------------------------------------------
__global__ void k_agg2_out(const int* __restrict__ rowoff, const int* __restrict__ srcs,
                           const float* __restrict__ s2, const float* __restrict__ dinv,
                           const float* __restrict__ W2, const float* __restrict__ b2,
                           const float* __restrict__ out_w, const float* __restrict__ out_b,
                           float* __restrict__ out) {
    __shared__ float lds[4][HID];
    int lane = threadIdx.x & 63;
    int w    = threadIdx.x >> 6;
    int g    = lane >> 4;
    int q    = lane & 15;
    int c0   = q * 4;
    int i    = blockIdx.x * 4 + w;
    int b = rowoff[i], en = rowoff[i + 1];
    float4 acc = {0.f, 0.f, 0.f, 0.f};
    for (int p = b + g; p < en; p += 4) {
        int s = srcs[p];
        const float4 v = *(const float4*)(s2 + (size_t)s * HID + c0);
        acc.x += v.x; acc.y += v.y; acc.z += v.z; acc.w += v.w;
    }
#pragma unroll
    for (int mask = 16; mask <= 32; mask <<= 1) {
        acc.x += __shfl_xor(acc.x, mask);
        acc.y += __shfl_xor(acc.y, mask);
        acc.z += __shfl_xor(acc.z, mask);
        acc.w += __shfl_xor(acc.w, mask);
    }
    if (g == 0) {
        float di = dinv[i];
        acc.x *= di; acc.y *= di; acc.z *= di; acc.w *= di;
        *(float4*)(&lds[w][c0]) = acc;
    }
    __syncthreads();
    float z = 0.f;
    const float4* row = (const float4*)lds[w];
#pragma unroll
    for (int j = 0; j < 16; ++j) {
        float4 h4 = row[j];
        z += h4.x * W2[(4 * j + 0) * HID + lane];
        z += h4.y * W2[(4 * j + 1) * HID + lane];
        z += h4.z * W2[(4 * j + 2) * HID + lane];
        z += h4.w * W2[(4 * j + 3) * HID + lane];
    }
    z = fmaxf(z + b2[lane], 0.f);
    float y = z * out_w[lane];  // out_w is (64,1) flat
    y += __shfl_xor(y, 32);
    y += __shfl_xor(y, 16);
    y += __shfl_xor(y, 8);
    y += __shfl_xor(y, 4);
    y += __shfl_xor(y, 2);
    y += __shfl_xor(y, 1);
    if (lane == 0) out[i] = y + out_b[0];
}

// ---------------------------------------------------------------------------

extern "C" void kernel_launch(void* const* d_in, const int* in_sizes, int n_in,
                              void* d_out, int out_size, void* d_ws, size_t ws_size,
                              hipStream_t stream) {
    const float* x   = (const float*)d_in[0];
    const int*   ei  = (const int*)d_in[1];
    const int*   src = ei;
    const int*   dst = ei + N_EDGES;
    const float* W1  = (const float*)d_in[2];
    const float* b1  = (const float*)d_in[3];
    const float* Wl  = (const float*)d_in[4];
    const float* Wr  = (const float*)d_in[5];
    const float* att = (const float*)d_in[6];
    const float* gb  = (const float*)d_in[7];
    const float* W2  = (const float*)d_in[8];
    const float* b2  = (const float*)d_in[9];
    const float* ow  = (const float*)d_in[10];
    const float* ob  = (const float*)d_in[11];
    float* out = (float*)d_out;

    // workspace layout (256B-aligned regions)
    char* ws = (char*)d_ws;
    size_t o = 0;
    auto alloc = [&](size_t bytes) { size_t r = o; o = (o + bytes + 255) & ~(size_t)255; return r; };
    int*   cnt     = (int*)  (ws + alloc((size_t)N_NODES * 4));
    int*   rowoff  = (int*)  (ws + alloc((size_t)(N_NODES + 1) * 4));
    int*   wcur    = (int*)  (ws + alloc((size_t)N_NODES * 4));
    int*   partial = (int*)  (ws + alloc(512 * 4));
    float* dinv    = (float*)(ws + alloc((size_t)N_NODES * 4));
    float* xs      = (float*)(ws + alloc((size_t)N_NODES * 4 * 4));
    float* aggx    = (float*)(ws + alloc((size_t)N_NODES * 4 * 4));
    int*   srcs    = (int*)  (ws + alloc((size_t)TOT_EDGES * 4));
    float* hl      = (float*)(ws + alloc((size_t)N_NODES * HID * 4));
    float* hr      = (float*)(ws + alloc((size_t)N_NODES * HID * 4));
    float* s2      = (float*)(ws + alloc((size_t)N_NODES * HID * 4));
    (void)ws_size; (void)n_in; (void)in_sizes; (void)out_size;

    const int nbN   = (N_NODES + 255) / 256;      // 391
    const int nbE   = (N_EDGES + 255) / 256;      // 6250
    const int nbTE  = (TOT_EDGES + 255) / 256;    // 6641
    const int nbW   = N_NODES / 4;                // 25000 (wave-per-node kernels, exact)
    const int nbW16 = N_NODES / 16;               // 6250  (4 nodes/wave kernels, exact)

    k_init_cnt<<<nbN, 256, 0, stream>>>(cnt);
    k_count<<<nbE, 256, 0, stream>>>(dst, cnt);
    k_scan1<<<nbN, 256, 0, stream>>>(cnt, partial);
    k_scan2<<<1, 512, 0, stream>>>(partial, nbN);
    k_scan3<<<nbN, 256, 0, stream>>>(cnt, partial, rowoff, wcur, dinv, x, xs);
    k_scatter<<<nbTE, 256, 0, stream>>>(src, dst, wcur, srcs);
    k_agg_x<<<nbW16, 256, 0, stream>>>(rowoff, srcs, xs, dinv, aggx);
    k_hlhr<<<nbW, 256, 0, stream>>>(aggx, W1, b1, Wl, Wr, hl, hr);
    k_gat<<<nbW, 256, 0, stream>>>(rowoff, srcs, hl, hr, att, gb, dinv, s2);
    k_agg2_out<<<nbW, 256, 0, stream>>>(rowoff, srcs, s2, dinv, W2, b2, ow, ob, out);
}

// Round 3
// 335.858 us; speedup vs baseline: 2.1492x; 1.4819x over previous
//
#include <hip/hip_runtime.h>
#include <math.h>

// Problem constants (match reference file)
#define N_NODES 100000
#define N_EDGES 1600000
#define TOT_EDGES (N_EDGES + N_NODES)   // with self-loops
#define HID 64
#define NB 391                          // node buckets of 256 (100000 >> 8 -> 0..390)

// ---------------------------------------------------------------------------
// Bucketed CSR build (sorted by dst).
// Stage 1: bucket histogram  Stage 2: bucket scan  Stage 3: binned pair scatter
// Stage 4: per-bucket node counts (LDS atomics)  Stage 5: node scan
// Stage 6: per-bucket CSR scatter (LDS cursors, writes stay in 17KB window)
// ---------------------------------------------------------------------------

__global__ void k_bin_count(const int* __restrict__ dst, int* __restrict__ bcnt) {
    __shared__ int hist[NB];
    for (int t = threadIdx.x; t < NB; t += blockDim.x) hist[t] = 0;
    __syncthreads();
    int stride = gridDim.x * blockDim.x;
    for (int e = blockIdx.x * blockDim.x + threadIdx.x; e < N_EDGES; e += stride)
        atomicAdd(&hist[dst[e] >> 8], 1);
    __syncthreads();
    for (int t = threadIdx.x; t < NB; t += blockDim.x)
        if (hist[t]) atomicAdd(&bcnt[t], hist[t]);
}

__global__ void k_bucket_scan(const int* __restrict__ bcnt, int* __restrict__ boff,
                              int* __restrict__ bcur) {
    __shared__ int lds[512];
    int t = threadIdx.x;
    int v = (t < NB) ? bcnt[t] : 0;
    lds[t] = v;
    __syncthreads();
    for (int off = 1; off < 512; off <<= 1) {
        int add = (t >= off) ? lds[t - off] : 0;
        __syncthreads();
        lds[t] += add;
        __syncthreads();
    }
    if (t < NB) { int excl = lds[t] - v; boff[t] = excl; bcur[t] = excl; }
    if (t == 0) boff[NB] = N_EDGES;
}

__global__ void k_bin_scatter(const int* __restrict__ src, const int* __restrict__ dst,
                              int* __restrict__ bcur, int2* __restrict__ binned) {
    __shared__ int hist[NB];
    __shared__ int base[NB];
    for (int t = threadIdx.x; t < NB; t += blockDim.x) hist[t] = 0;
    __syncthreads();
    int stride = gridDim.x * blockDim.x;
    int gid = blockIdx.x * blockDim.x + threadIdx.x;
    for (int e = gid; e < N_EDGES; e += stride)
        atomicAdd(&hist[dst[e] >> 8], 1);
    __syncthreads();
    for (int t = threadIdx.x; t < NB; t += blockDim.x) {
        int h = hist[t];
        base[t] = h ? atomicAdd(&bcur[t], h) : 0;
        hist[t] = 0;
    }
    __syncthreads();
    for (int e = gid; e < N_EDGES; e += stride) {
        int d = dst[e];
        int bkt = d >> 8;
        int off = base[bkt] + atomicAdd(&hist[bkt], 1);
        binned[off] = make_int2(src[e], d);
    }
}

__global__ void k_node_count(const int2* __restrict__ binned, const int* __restrict__ boff,
                             int* __restrict__ cnt) {
    __shared__ int c[256];
    int b = blockIdx.x;
    int n0 = b << 8;
    int nn = min(256, N_NODES - n0);
    c[threadIdx.x] = 1;  // self-loop
    __syncthreads();
    int e0 = boff[b], e1 = boff[b + 1];
    for (int i = e0 + threadIdx.x; i < e1; i += blockDim.x)
        atomicAdd(&c[binned[i].y & 255], 1);
    __syncthreads();
    if (threadIdx.x < nn) cnt[n0 + threadIdx.x] = c[threadIdx.x];
}

__global__ void k_csr_scatter(const int2* __restrict__ binned, const int* __restrict__ boff,
                              const int* __restrict__ rowoff, int* __restrict__ srcs) {
    __shared__ int cur[256];
    int b = blockIdx.x;
    int n0 = b << 8;
    int nn = min(256, N_NODES - n0);
    if (threadIdx.x < nn) cur[threadIdx.x] = rowoff[n0 + threadIdx.x];
    __syncthreads();
    int e0 = boff[b], e1 = boff[b + 1];
    for (int i = e0 + threadIdx.x; i < e1; i += blockDim.x) {
        int2 p = binned[i];
        int pos = atomicAdd(&cur[p.y & 255], 1);
        srcs[pos] = p.x;
    }
    __syncthreads();
    if (threadIdx.x < nn) srcs[cur[threadIdx.x]] = n0 + threadIdx.x;  // self-loop (last slot)
}

// ---------------------------------------------------------------------------
// Node scans: block partials -> scan partials -> apply (+ dinv, xs fused)
// ---------------------------------------------------------------------------

__global__ void k_scan1(const int* __restrict__ cnt, int* __restrict__ partial) {
    __shared__ int lds[256];
    int i = blockIdx.x * 256 + threadIdx.x;
    int v = (i < N_NODES) ? cnt[i] : 0;
    lds[threadIdx.x] = v;
    __syncthreads();
    for (int s = 128; s > 0; s >>= 1) {
        if (threadIdx.x < s) lds[threadIdx.x] += lds[threadIdx.x + s];
        __syncthreads();
    }
    if (threadIdx.x == 0) partial[blockIdx.x] = lds[0];
}

__global__ void k_scan2(int* __restrict__ partial, int nb) {
    __shared__ int lds[512];
    int t = threadIdx.x;
    int v = (t < nb) ? partial[t] : 0;
    lds[t] = v;
    __syncthreads();
    for (int off = 1; off < 512; off <<= 1) {
        int add = (t >= off) ? lds[t - off] : 0;
        __syncthreads();
        lds[t] += add;
        __syncthreads();
    }
    if (t < nb) partial[t] = lds[t] - v;  // exclusive
}

__global__ void k_scan3(const int* __restrict__ cnt, const int* __restrict__ partial,
                        int* __restrict__ rowoff, float* __restrict__ dinv,
                        const float* __restrict__ x, float* __restrict__ xs) {
    __shared__ int lds[256];
    int i = blockIdx.x * 256 + threadIdx.x;
    int v = (i < N_NODES) ? cnt[i] : 0;
    lds[threadIdx.x] = v;
    __syncthreads();
    for (int off = 1; off < 256; off <<= 1) {
        int add = (threadIdx.x >= off) ? lds[threadIdx.x - off] : 0;
        __syncthreads();
        lds[threadIdx.x] += add;
        __syncthreads();
    }
    if (i < N_NODES) {
        int excl = partial[blockIdx.x] + lds[threadIdx.x] - v;
        rowoff[i] = excl;
        float di = rsqrtf((float)v);  // deg >= 1 always (self-loop)
        dinv[i] = di;
        float4 xv = ((const float4*)x)[i];
        xv.x *= di; xv.y *= di; xv.z *= di; xv.w *= di;
        ((float4*)xs)[i] = xv;
        if (i == N_NODES - 1) rowoff[N_NODES] = excl + v;
    }
}

// ---------------------------------------------------------------------------
// GCN1 aggregation in 4-channel input space.
// Wave handles 4 nodes (16 lanes each, edge-per-lane float4 gathers).
// ---------------------------------------------------------------------------
__global__ void k_agg_x(const int* __restrict__ rowoff, const int* __restrict__ srcs,
                        const float* __restrict__ xs, const float* __restrict__ dinv,
                        float* __restrict__ aggx) {
    int lane = threadIdx.x & 63;
    int w    = threadIdx.x >> 6;
    int g    = lane >> 4;   // node within wave
    int q    = lane & 15;   // edge slot
    int i    = blockIdx.x * 16 + w * 4 + g;
    int b = rowoff[i], en = rowoff[i + 1];
    float4 acc = {0.f, 0.f, 0.f, 0.f};
    for (int p = b + q; p < en; p += 16) {
        int s = srcs[p];
        float4 v = ((const float4*)xs)[s];
        acc.x += v.x; acc.y += v.y; acc.z += v.z; acc.w += v.w;
    }
#pragma unroll
    for (int mask = 1; mask <= 8; mask <<= 1) {
        acc.x += __shfl_xor(acc.x, mask);
        acc.y += __shfl_xor(acc.y, mask);
        acc.z += __shfl_xor(acc.z, mask);
        acc.w += __shfl_xor(acc.w, mask);
    }
    if (q == 0) {
        float di = dinv[i];
        acc.x *= di; acc.y *= di; acc.z *= di; acc.w *= di;
        ((float4*)aggx)[i] = acc;
    }
}

// ---------------------------------------------------------------------------
// h1 = relu(aggx @ W1 + b1); hl = h1 @ Wl; hr = h1 @ Wr   (wave per node)
// ---------------------------------------------------------------------------
__global__ void k_hlhr(const float* __restrict__ aggx, const float* __restrict__ W1,
                       const float* __restrict__ b1, const float* __restrict__ Wl,
                       const float* __restrict__ Wr, float* __restrict__ hl,
                       float* __restrict__ hr) {
    __shared__ float lds[4][HID];
    int lane = threadIdx.x & 63;
    int w    = threadIdx.x >> 6;
    int i    = blockIdx.x * 4 + w;
    float4 a = ((const float4*)aggx)[i];
    float h = a.x * W1[0 * HID + lane] + a.y * W1[1 * HID + lane] +
              a.z * W1[2 * HID + lane] + a.w * W1[3 * HID + lane] + b1[lane];
    h = fmaxf(h, 0.f);
    lds[w][lane] = h;
    __syncthreads();
    float al = 0.f, ar = 0.f;
#pragma unroll 8
    for (int k = 0; k < HID; ++k) {
        float t = lds[w][k];
        al += t * Wl[k * HID + lane];
        ar += t * Wr[k * HID + lane];
    }
    hl[i * HID + lane] = al;
    hr[i * HID + lane] = ar;
}

// ---------------------------------------------------------------------------
// GATv2 online softmax, 2x unrolled: 8 row-gathers in flight per wave.
// Lane l: edge group g=l>>4, channel quad q=l&15 (c0=4q, head=q>>3).
// ---------------------------------------------------------------------------
__global__ void k_gat(const int* __restrict__ rowoff, const int* __restrict__ srcs,
                      const float* __restrict__ hl, const float* __restrict__ hr,
                      const float* __restrict__ att, const float* __restrict__ gat_b,
                      const float* __restrict__ dinv, float* __restrict__ s2) {
    int lane = threadIdx.x & 63;
    int w    = threadIdx.x >> 6;
    int g    = lane >> 4;
    int q    = lane & 15;
    int c0   = q * 4;
    int i    = blockIdx.x * 4 + w;
    const float4 hri = *(const float4*)(hr + (size_t)i * HID + c0);
    const float4 a4  = *(const float4*)(att + c0);
    float  m = -1e30f, denom = 0.f;
    float4 acc = {0.f, 0.f, 0.f, 0.f};
    int b = rowoff[i], en = rowoff[i + 1];
    int p = b + g;
    for (; p + 4 < en; p += 8) {
        int s0 = srcs[p];
        int s1 = srcs[p + 4];
        const float4 v0 = *(const float4*)(hl + (size_t)s0 * HID + c0);
        const float4 v1 = *(const float4*)(hl + (size_t)s1 * HID + c0);
        float ex0, ey0, ez0, ew0, ex1, ey1, ez1, ew1;
        ex0 = v0.x + hri.x; ey0 = v0.y + hri.y; ez0 = v0.z + hri.z; ew0 = v0.w + hri.w;
        ex1 = v1.x + hri.x; ey1 = v1.y + hri.y; ez1 = v1.z + hri.z; ew1 = v1.w + hri.w;
        ex0 = (ex0 > 0.f) ? ex0 : 0.2f * ex0; ey0 = (ey0 > 0.f) ? ey0 : 0.2f * ey0;
        ez0 = (ez0 > 0.f) ? ez0 : 0.2f * ez0; ew0 = (ew0 > 0.f) ? ew0 : 0.2f * ew0;
        ex1 = (ex1 > 0.f) ? ex1 : 0.2f * ex1; ey1 = (ey1 > 0.f) ? ey1 : 0.2f * ey1;
        ez1 = (ez1 > 0.f) ? ez1 : 0.2f * ez1; ew1 = (ew1 > 0.f) ? ew1 : 0.2f * ew1;
        float t0 = ex0 * a4.x + ey0 * a4.y + ez0 * a4.z + ew0 * a4.w;
        float t1 = ex1 * a4.x + ey1 * a4.y + ez1 * a4.z + ew1 * a4.w;
        t0 += __shfl_xor(t0, 1); t1 += __shfl_xor(t1, 1);
        t0 += __shfl_xor(t0, 2); t1 += __shfl_xor(t1, 2);
        t0 += __shfl_xor(t0, 4); t1 += __shfl_xor(t1, 4);
        float nm = fmaxf(m, t0);
        float sc = __expf(m - nm);
        float ex = __expf(t0 - nm);
        denom = denom * sc + ex;
        acc.x = acc.x * sc + ex * v0.x;
        acc.y = acc.y * sc + ex * v0.y;
        acc.z = acc.z * sc + ex * v0.z;
        acc.w = acc.w * sc + ex * v0.w;
        m = nm;
        nm = fmaxf(m, t1);
        sc = __expf(m - nm);
        ex = __expf(t1 - nm);
        denom = denom * sc + ex;
        acc.x = acc.x * sc + ex * v1.x;
        acc.y = acc.y * sc + ex * v1.y;
        acc.z = acc.z * sc + ex * v1.z;
        acc.w = acc.w * sc + ex * v1.w;
        m = nm;
    }
    if (p < en) {
        int s = srcs[p];
        const float4 v = *(const float4*)(hl + (size_t)s * HID + c0);
        float ex0 = v.x + hri.x, ey0 = v.y + hri.y, ez0 = v.z + hri.z, ew0 = v.w + hri.w;
        ex0 = (ex0 > 0.f) ? ex0 : 0.2f * ex0; ey0 = (ey0 > 0.f) ? ey0 : 0.2f * ey0;
        ez0 = (ez0 > 0.f) ? ez0 : 0.2f * ez0; ew0 = (ew0 > 0.f) ? ew0 : 0.2f * ew0;
        float t0 = ex0 * a4.x + ey0 * a4.y + ez0 * a4.z + ew0 * a4.w;
        t0 += __shfl_xor(t0, 1);
        t0 += __shfl_xor(t0, 2);
        t0 += __shfl_xor(t0, 4);
        float nm = fmaxf(m, t0);
        float sc = __expf(m - nm);
        float ex = __expf(t0 - nm);
        denom = denom * sc + ex;
        acc.x = acc.x * sc + ex * v.x;
        acc.y = acc.y * sc + ex * v.y;
        acc.z = acc.z * sc + ex * v.z;
        acc.w = acc.w * sc + ex * v.w;
        m = nm;
    }
    // merge the 4 groups' online states (same q -> same channels/head)
#pragma unroll
    for (int mask = 16; mask <= 32; mask <<= 1) {
        float m2 = __shfl_xor(m, mask);
        float d2 = __shfl_xor(denom, mask);
        float ax = __shfl_xor(acc.x, mask);
        float ay = __shfl_xor(acc.y, mask);
        float az = __shfl_xor(acc.z, mask);
        float aw = __shfl_xor(acc.w, mask);
        float nm = fmaxf(m, m2);
        float sa = __expf(m - nm);
        float sb = __expf(m2 - nm);
        denom = denom * sa + d2 * sb;
        acc.x = acc.x * sa + ax * sb;
        acc.y = acc.y * sa + ay * sb;
        acc.z = acc.z * sa + az * sb;
        acc.w = acc.w * sa + aw * sb;
        m = nm;
    }
    float inv = 1.f / (denom + 1e-16f);
    const float4 gb = *(const float4*)(gat_b + c0);
    float di = dinv[i];
    float4 o;
    o.x = fmaxf(acc.x * inv + gb.x, 0.f) * di;
    o.y = fmaxf(acc.y * inv + gb.y, 0.f) * di;
    o.z = fmaxf(acc.z * inv + gb.z, 0.f) * di;
    o.w = fmaxf(acc.w * inv + gb.w, 0.f) * di;
    if (g == 0) *(float4*)(s2 + (size_t)i * HID + c0) = o;
}

// ---------------------------------------------------------------------------
// GCN2 aggregation + transform + bias + relu + final linear, all fused.
// 2x unrolled gather: 8 rows in flight per wave.
// ---------------------------------------------------------------------------
__global__ void k_agg2_out(const int* __restrict__ rowoff, const int* __restrict__ srcs,
                           const float* __restrict__ s2, const float* __restrict__ dinv,
                           const float* __restrict__ W2, const float* __restrict__ b2,
                           const float* __restrict__ out_w, const float* __restrict__ out_b,
                           float* __restrict__ out) {
    __shared__ float lds[4][HID];
    int lane = threadIdx.x & 63;
    int w    = threadIdx.x >> 6;
    int g    = lane >> 4;
    int q    = lane & 15;
    int c0   = q * 4;
    int i    = blockIdx.x * 4 + w;
    int b = rowoff[i], en = rowoff[i + 1];
    float4 acc = {0.f, 0.f, 0.f, 0.f};
    int p = b + g;
    for (; p + 4 < en; p += 8) {
        int s0 = srcs[p];
        int s1 = srcs[p + 4];
        const float4 v0 = *(const float4*)(s2 + (size_t)s0 * HID + c0);
        const float4 v1 = *(const float4*)(s2 + (size_t)s1 * HID + c0);
        acc.x += v0.x + v1.x; acc.y += v0.y + v1.y;
        acc.z += v0.z + v1.z; acc.w += v0.w + v1.w;
    }
    if (p < en) {
        int s = srcs[p];
        const float4 v = *(const float4*)(s2 + (size_t)s * HID + c0);
        acc.x += v.x; acc.y += v.y; acc.z += v.z; acc.w += v.w;
    }
#pragma unroll
    for (int mask = 16; mask <= 32; mask <<= 1) {
        acc.x += __shfl_xor(acc.x, mask);
        acc.y += __shfl_xor(acc.y, mask);
        acc.z += __shfl_xor(acc.z, mask);
        acc.w += __shfl_xor(acc.w, mask);
    }
    if (g == 0) {
        float di = dinv[i];
        acc.x *= di; acc.y *= di; acc.z *= di; acc.w *= di;
        *(float4*)(&lds[w][c0]) = acc;
    }
    __syncthreads();
    float z = 0.f;
    const float4* row = (const float4*)lds[w];
#pragma unroll
    for (int j = 0; j < 16; ++j) {
        float4 h4 = row[j];
        z += h4.x * W2[(4 * j + 0) * HID + lane];
        z += h4.y * W2[(4 * j + 1) * HID + lane];
        z += h4.z * W2[(4 * j + 2) * HID + lane];
        z += h4.w * W2[(4 * j + 3) * HID + lane];
    }
    z = fmaxf(z + b2[lane], 0.f);
    float y = z * out_w[lane];  // out_w is (64,1) flat
    y += __shfl_xor(y, 32);
    y += __shfl_xor(y, 16);
    y += __shfl_xor(y, 8);
    y += __shfl_xor(y, 4);
    y += __shfl_xor(y, 2);
    y += __shfl_xor(y, 1);
    if (lane == 0) out[i] = y + out_b[0];
}

// ---------------------------------------------------------------------------

extern "C" void kernel_launch(void* const* d_in, const int* in_sizes, int n_in,
                              void* d_out, int out_size, void* d_ws, size_t ws_size,
                              hipStream_t stream) {
    const float* x   = (const float*)d_in[0];
    const int*   ei  = (const int*)d_in[1];
    const int*   src = ei;
    const int*   dst = ei + N_EDGES;
    const float* W1  = (const float*)d_in[2];
    const float* b1  = (const float*)d_in[3];
    const float* Wl  = (const float*)d_in[4];
    const float* Wr  = (const float*)d_in[5];
    const float* att = (const float*)d_in[6];
    const float* gb  = (const float*)d_in[7];
    const float* W2  = (const float*)d_in[8];
    const float* b2  = (const float*)d_in[9];
    const float* ow  = (const float*)d_in[10];
    const float* ob  = (const float*)d_in[11];
    float* out = (float*)d_out;

    // workspace layout (256B-aligned regions)
    char* ws = (char*)d_ws;
    size_t o = 0;
    auto alloc = [&](size_t bytes) { size_t r = o; o = (o + bytes + 255) & ~(size_t)255; return r; };
    int*   cnt     = (int*)  (ws + alloc((size_t)N_NODES * 4));
    int*   rowoff  = (int*)  (ws + alloc((size_t)(N_NODES + 1) * 4));
    int*   partial = (int*)  (ws + alloc(512 * 4));
    int*   bcnt    = (int*)  (ws + alloc((size_t)NB * 4));
    int*   boff    = (int*)  (ws + alloc((size_t)(NB + 1) * 4));
    int*   bcur    = (int*)  (ws + alloc((size_t)NB * 4));
    float* dinv    = (float*)(ws + alloc((size_t)N_NODES * 4));
    float* xs      = (float*)(ws + alloc((size_t)N_NODES * 4 * 4));
    float* aggx    = (float*)(ws + alloc((size_t)N_NODES * 4 * 4));
    int2*  binned  = (int2*) (ws + alloc((size_t)N_EDGES * 8));
    int*   srcs    = (int*)  (ws + alloc((size_t)TOT_EDGES * 4));
    float* hl      = (float*)(ws + alloc((size_t)N_NODES * HID * 4));
    float* hr      = (float*)(ws + alloc((size_t)N_NODES * HID * 4));
    float* s2      = (float*)(ws + alloc((size_t)N_NODES * HID * 4));
    (void)ws_size; (void)n_in; (void)in_sizes; (void)out_size;

    const int nbN   = (N_NODES + 255) / 256;      // 391
    const int nbW   = N_NODES / 4;                // 25000 (wave-per-node kernels, exact)
    const int nbW16 = N_NODES / 16;               // 6250  (4 nodes/wave kernels, exact)

    hipMemsetAsync(bcnt, 0, (size_t)NB * 4, stream);
    k_bin_count<<<128, 1024, 0, stream>>>(dst, bcnt);
    k_bucket_scan<<<1, 512, 0, stream>>>(bcnt, boff, bcur);
    k_bin_scatter<<<128, 1024, 0, stream>>>(src, dst, bcur, binned);
    k_node_count<<<NB, 256, 0, stream>>>(binned, boff, cnt);
    k_scan1<<<nbN, 256, 0, stream>>>(cnt, partial);
    k_scan2<<<1, 512, 0, stream>>>(partial, nbN);
    k_scan3<<<nbN, 256, 0, stream>>>(cnt, partial, rowoff, dinv, x, xs);
    k_csr_scatter<<<NB, 256, 0, stream>>>(binned, boff, rowoff, srcs);
    k_agg_x<<<nbW16, 256, 0, stream>>>(rowoff, srcs, xs, dinv, aggx);
    k_hlhr<<<nbW, 256, 0, stream>>>(aggx, W1, b1, Wl, Wr, hl, hr);
    k_gat<<<nbW, 256, 0, stream>>>(rowoff, srcs, hl, hr, att, gb, dinv, s2);
    k_agg2_out<<<nbW, 256, 0, stream>>>(rowoff, srcs, s2, dinv, W2, b2, ow, ob, out);
}